// Round 5
// baseline (236.230 us; speedup 1.0000x reference)
//
#include <hip/hip_runtime.h>

#define T_TOTAL 4194304
#define BLK 256
#define PER_TH 8
#define CHUNK (BLK * PER_TH)      // 2048 elements per block
#define NB (T_TOTAL / CHUNK)      // 2048 chunks
#define NWAVE (BLK / 64)          // 4 waves per block
#define SBLK 512                  // k_scan block size
#define SWAVE (SBLK / 64)         // 8 waves
#define SPER (NB / SBLK)          // 4 aggregates per scan thread
#define SCOPE __HIP_MEMORY_SCOPE_AGENT

// Affine transform convention: T_i maps v_{i+1} -> v_i = a_i*v_{i+1} + d_i.
// Fold over increasing i: D = fmaf(A, d_i, D); A *= a_i.

// ---- pass 1: compute (a,d), spill interleaved to ws, emit chunk aggregates ----
__global__ __launch_bounds__(BLK) void k_agg(
    const float* __restrict__ lp, const float* __restrict__ olp,
    const float* __restrict__ val, const float* __restrict__ nval,
    const float* __restrict__ rew, const float* __restrict__ ter,
    float* __restrict__ ad,       // interleaved: ad[2e]=a_e, ad[2e+1]=d_e
    float* __restrict__ bA, float* __restrict__ bD)
{
    __shared__ float wA[NWAVE], wD[NWAVE];
    const int b = blockIdx.x, t = threadIdx.x;
    const int lane = t & 63, w = t >> 6;
    const size_t base4 = (size_t)b * (CHUNK / 4) + 2 * (size_t)t;  // 2 float4s/thread
    float4* __restrict__ ad4 = (float4*)ad;                        // 2 elems per float4

    float A = 1.0f, D = 0.0f;
#pragma unroll
    for (int k = 0; k < 2; ++k) {
        const float4 L = ((const float4*)lp)[base4 + k];
        const float4 O = ((const float4*)olp)[base4 + k];
        const float4 V = ((const float4*)val)[base4 + k];
        const float4 N = ((const float4*)nval)[base4 + k];
        const float4 R = ((const float4*)rew)[base4 + k];
        const float4 Tm = ((const float4*)ter)[base4 + k];
        const float Ls[4] = {L.x, L.y, L.z, L.w};
        const float Os[4] = {O.x, O.y, O.z, O.w};
        const float Vs[4] = {V.x, V.y, V.z, V.w};
        const float Ns[4] = {N.x, N.y, N.z, N.w};
        const float Rs[4] = {R.x, R.y, R.z, R.w};
        const float Ts[4] = {Tm.x, Tm.y, Tm.z, Tm.w};
        float av[4], dv[4];
#pragma unroll
        for (int i = 0; i < 4; ++i) {
            const float rho = fminf(1.0f, __expf(Ls[i] - Os[i]));
            av[i] = Ts[i] * rho;
            dv[i] = rho * (Rs[i] + Ts[i] * Ns[i] - Vs[i]);
            D = fmaf(A, dv[i], D);
            A *= av[i];
        }
        // spill: 2 float4s per input-float4 (a,d interleaved)
        ad4[2 * (base4 + k) + 0] = make_float4(av[0], dv[0], av[1], dv[1]);
        ad4[2 * (base4 + k) + 1] = make_float4(av[2], dv[2], av[3], dv[3]);
    }

    // wave suffix compose -> lane 0 holds wave total
    float iA = A, iD = D;
#pragma unroll
    for (int s = 1; s < 64; s <<= 1) {
        const float oA = __shfl_down(iA, s);
        const float oD = __shfl_down(iD, s);
        if (lane + s < 64) { iD = fmaf(iA, oD, iD); iA *= oA; }
    }
    if (lane == 0) { wA[w] = iA; wD[w] = iD; }
    __syncthreads();
    if (t == 0) {
        float BA = 1.0f, BD = 0.0f;
#pragma unroll
        for (int j = 0; j < NWAVE; ++j) { BD = fmaf(BA, wD[j], BD); BA *= wA[j]; }
        bA[b] = BA; bD[b] = BD;
    }
}

// ---- pass 2: scan over 2048 chunk aggregates; zero acc/done ----
__global__ __launch_bounds__(SBLK) void k_scan(
    const float* __restrict__ bA, const float* __restrict__ bD,
    float* __restrict__ carry, double* __restrict__ acc, unsigned* __restrict__ done)
{
    __shared__ float wA[SWAVE], wD[SWAVE];
    const int t = threadIdx.x;
    const int lane = t & 63, w = t >> 6;
    if (t == 0) { *acc = 0.0; *done = 0u; }   // ws is poisoned before every launch

    float a4[SPER], d4[SPER];
    {
        const float4 A4 = ((const float4*)bA)[t];
        const float4 D4 = ((const float4*)bD)[t];
        a4[0] = A4.x; a4[1] = A4.y; a4[2] = A4.z; a4[3] = A4.w;
        d4[0] = D4.x; d4[1] = D4.y; d4[2] = D4.z; d4[3] = D4.w;
    }
    float A = 1.0f, D = 0.0f;
#pragma unroll
    for (int i = 0; i < SPER; ++i) { D = fmaf(A, d4[i], D); A *= a4[i]; }

    float iA = A, iD = D;
#pragma unroll
    for (int s = 1; s < 64; s <<= 1) {
        const float oA = __shfl_down(iA, s);
        const float oD = __shfl_down(iD, s);
        if (lane + s < 64) { iD = fmaf(iA, oD, iD); iA *= oA; }
    }
    if (lane == 0) { wA[w] = iA; wD[w] = iD; }
    __syncthreads();

    float SA = 1.0f, SD = 0.0f;
#pragma unroll
    for (int j = 0; j < SWAVE; ++j) {
        if (j > w) { SD = fmaf(SA, wD[j], SD); SA *= wA[j]; }
    }

    float eA = __shfl_down(iA, 1);
    float eD = __shfl_down(iD, 1);
    if (lane == 63) { eA = 1.0f; eD = 0.0f; }
    const float ED = fmaf(eA, SD, eD);       // applied to v=0 -> only D matters

    float c4[SPER];
    float v = ED;
    c4[SPER - 1] = v;
#pragma unroll
    for (int i = SPER - 1; i > 0; --i) { v = fmaf(a4[i], v, d4[i]); c4[i - 1] = v; }
    ((float4*)carry)[t] = make_float4(c4[0], c4[1], c4[2], c4[3]);
}

// ---- pass 3: read (a,d) spill, apply carries, write ys + fused loss ----
__global__ __launch_bounds__(BLK) void k_out(
    const float* __restrict__ ad, const float* __restrict__ carry,
    float* __restrict__ out, double* __restrict__ acc, unsigned* __restrict__ done)
{
    __shared__ float wA[NWAVE], wD[NWAVE], rsum[NWAVE];
    __shared__ float sv[CHUNK];
    __shared__ float sVin;

    const int b = blockIdx.x, t = threadIdx.x;
    const int lane = t & 63, w = t >> 6;
    const float4* __restrict__ ad4 = (const float4*)ad;
    const size_t abase = (size_t)b * (CHUNK / 2) + 4 * (size_t)t;  // 4 f4 = 8 elems

    float a[PER_TH], d[PER_TH];
#pragma unroll
    for (int k = 0; k < 4; ++k) {
        const float4 P = ad4[abase + k];
        a[2 * k + 0] = P.x; d[2 * k + 0] = P.y;
        a[2 * k + 1] = P.z; d[2 * k + 1] = P.w;
    }

    float A = 1.0f, D = 0.0f;
#pragma unroll
    for (int i = 0; i < PER_TH; ++i) { D = fmaf(A, d[i], D); A *= a[i]; }

    float iA = A, iD = D;
#pragma unroll
    for (int s = 1; s < 64; s <<= 1) {
        const float oA = __shfl_down(iA, s);
        const float oD = __shfl_down(iD, s);
        if (lane + s < 64) { iD = fmaf(iA, oD, iD); iA *= oA; }
    }
    if (lane == 0) { wA[w] = iA; wD[w] = iD; }
    if (t == 0) sVin = carry[b];
    __syncthreads();                               // barrier 1

    float SA = 1.0f, SD = 0.0f;
#pragma unroll
    for (int j = 0; j < NWAVE; ++j) {
        if (j > w) { SD = fmaf(SA, wD[j], SD); SA *= wA[j]; }
    }
    float eA = __shfl_down(iA, 1);
    float eD = __shfl_down(iD, 1);
    if (lane == 63) { eA = 1.0f; eD = 0.0f; }
    const float EA = eA * SA;
    const float ED = fmaf(eA, SD, eD);
    const float vin = sVin;

    float v = fmaf(EA, vin, ED);
    float ss = 0.0f;
#pragma unroll
    for (int i = PER_TH - 1; i >= 0; --i) {
        v = fmaf(a[i], v, d[i]);
        d[i] = v;
        ss = fmaf(v, v, ss);
    }

    // stage in LDS, coalesced scalar stores (out+1 is 4B-misaligned for float4)
#pragma unroll
    for (int k = 0; k < 2; ++k)
        ((float4*)sv)[2 * t + k] =
            make_float4(d[4*k+0], d[4*k+1], d[4*k+2], d[4*k+3]);
    __syncthreads();                               // barrier 2
    const size_t obase = 1 + (size_t)b * CHUNK;
#pragma unroll
    for (int k = 0; k < PER_TH; ++k) out[obase + t + k * BLK] = sv[t + k * BLK];

    // loss: wave butterfly -> LDS -> one double atomic/block; last block finalizes
#pragma unroll
    for (int s = 32; s > 0; s >>= 1) ss += __shfl_xor(ss, s);
    if (lane == 0) rsum[w] = ss;
    __syncthreads();                               // barrier 3
    if (t == 0) {
        float bs = 0.0f;
#pragma unroll
        for (int j = 0; j < NWAVE; ++j) bs += rsum[j];
        atomicAdd(acc, (double)bs);
        __threadfence();
        const unsigned old = atomicAdd(done, 1u);
        if (old == NB - 1) {
            const double av = __hip_atomic_load(acc, __ATOMIC_ACQUIRE, SCOPE);
            out[0] = (float)(av * (1.0 / (double)T_TOTAL));
        }
    }
}

extern "C" void kernel_launch(void* const* d_in, const int* in_sizes, int n_in,
                              void* d_out, int out_size, void* d_ws, size_t ws_size,
                              hipStream_t stream) {
    const float* lp   = (const float*)d_in[0];
    const float* olp  = (const float*)d_in[1];
    const float* val  = (const float*)d_in[2];
    const float* nval = (const float*)d_in[3];
    const float* rew  = (const float*)d_in[4];
    const float* ter  = (const float*)d_in[5];
    float* out = (float*)d_out;

    double*   acc   = (double*)d_ws;                    // 8B
    unsigned* done  = (unsigned*)((char*)d_ws + 8);     // 4B (+4 pad)
    float*    bA    = (float*)((char*)d_ws + 16);       // NB floats
    float*    bD    = bA + NB;
    float*    carry = bD + NB;
    float*    ad    = carry + NB;                       // 2*T floats = 33.6 MB
    // total ws use: 16 + 3*NB*4 + 8*T_TOTAL bytes ≈ 33.6 MB (ws is 256 MiB)

    k_agg <<<NB, BLK, 0, stream>>>(lp, olp, val, nval, rew, ter, ad, bA, bD);
    k_scan<<<1, SBLK, 0, stream>>>(bA, bD, carry, acc, done);
    k_out <<<NB, BLK, 0, stream>>>(ad, carry, out, acc, done);
}

// Round 6
// 230.829 us; speedup vs baseline: 1.0234x; 1.0234x over previous
//
#include <hip/hip_runtime.h>

#define T_TOTAL 4194304
#define BLK 256
#define PER_TH 8
#define CHUNK (BLK * PER_TH)      // 2048 elements per block
#define NB (T_TOTAL / CHUNK)      // 2048 chunks
#define NWAVE (BLK / 64)          // 4 waves per block
#define SCOPE __HIP_MEMORY_SCOPE_AGENT

// Affine transform: T_i maps v_{i+1} -> v_i = a_i*v_{i+1} + d_i.
// Fold over increasing i: D = fmaf(A, d_i, D); A *= a_i.
// Suffix-combine (self=lower idx, other=higher): D = fmaf(A, oD, D); A *= oA.

// ---- pass 1: per-chunk aggregates (pure stream; no heavy state across barrier) ----
__global__ __launch_bounds__(BLK) void k_agg(
    const float* __restrict__ lp, const float* __restrict__ olp,
    const float* __restrict__ val, const float* __restrict__ nval,
    const float* __restrict__ rew, const float* __restrict__ ter,
    float* __restrict__ bA, float* __restrict__ bD,
    double* __restrict__ acc, unsigned* __restrict__ done)
{
    __shared__ float wA[NWAVE], wD[NWAVE];
    const int b = blockIdx.x, t = threadIdx.x;
    const int lane = t & 63, w = t >> 6;
    const size_t base4 = (size_t)b * (CHUNK / 4) + 2 * (size_t)t;

    if (b == 0 && t == 0) { *acc = 0.0; *done = 0u; }   // ws poisoned pre-launch

    float A = 1.0f, D = 0.0f;
#pragma unroll
    for (int k = 0; k < 2; ++k) {
        const float4 L = ((const float4*)lp)[base4 + k];
        const float4 O = ((const float4*)olp)[base4 + k];
        const float4 V = ((const float4*)val)[base4 + k];
        const float4 N = ((const float4*)nval)[base4 + k];
        const float4 R = ((const float4*)rew)[base4 + k];
        const float4 Tm = ((const float4*)ter)[base4 + k];
        const float Ls[4] = {L.x, L.y, L.z, L.w};
        const float Os[4] = {O.x, O.y, O.z, O.w};
        const float Vs[4] = {V.x, V.y, V.z, V.w};
        const float Ns[4] = {N.x, N.y, N.z, N.w};
        const float Rs[4] = {R.x, R.y, R.z, R.w};
        const float Ts[4] = {Tm.x, Tm.y, Tm.z, Tm.w};
#pragma unroll
        for (int i = 0; i < 4; ++i) {
            const float rho = fminf(1.0f, __expf(Ls[i] - Os[i]));
            const float ai = Ts[i] * rho;
            const float di = rho * (Rs[i] + Ts[i] * Ns[i] - Vs[i]);
            D = fmaf(A, di, D);
            A *= ai;
        }
    }

    float iA = A, iD = D;
#pragma unroll
    for (int s = 1; s < 64; s <<= 1) {
        const float oA = __shfl_down(iA, s);
        const float oD = __shfl_down(iD, s);
        if (lane + s < 64) { iD = fmaf(iA, oD, iD); iA *= oA; }
    }
    if (lane == 0) { wA[w] = iA; wD[w] = iD; }
    __syncthreads();
    if (t == 0) {
        float BA = 1.0f, BD = 0.0f;
#pragma unroll
        for (int j = 0; j < NWAVE; ++j) { BD = fmaf(BA, wD[j], BD); BA *= wA[j]; }
        bA[b] = BA; bD[b] = BD;
    }
}

// ---- pass 2: recompute a,d; LDS round-trip across the scan barrier; outputs + loss ----
__global__ __launch_bounds__(BLK) void k_out(
    const float* __restrict__ lp, const float* __restrict__ olp,
    const float* __restrict__ val, const float* __restrict__ nval,
    const float* __restrict__ rew, const float* __restrict__ ter,
    const float* __restrict__ bA, const float* __restrict__ bD,
    float* __restrict__ out, double* __restrict__ acc, unsigned* __restrict__ done)
{
    __shared__ float aL[CHUNK], dL[CHUNK];               // 16 KB
    __shared__ float wA[NWAVE], wD[NWAVE], rsum[NWAVE];
    __shared__ float sVin;

    const int b = blockIdx.x, t = threadIdx.x;
    const int lane = t & 63, w = t >> 6;
    const size_t base4 = (size_t)b * (CHUNK / 4) + 2 * (size_t)t;

    // ---- phase A: load inputs, compute a,d, stash to LDS, fold to (A,D) ----
    float a[PER_TH], d[PER_TH];
#pragma unroll
    for (int k = 0; k < 2; ++k) {
        const float4 L = ((const float4*)lp)[base4 + k];
        const float4 O = ((const float4*)olp)[base4 + k];
        const float4 V = ((const float4*)val)[base4 + k];
        const float4 N = ((const float4*)nval)[base4 + k];
        const float4 R = ((const float4*)rew)[base4 + k];
        const float4 Tm = ((const float4*)ter)[base4 + k];
        const float Ls[4] = {L.x, L.y, L.z, L.w};
        const float Os[4] = {O.x, O.y, O.z, O.w};
        const float Vs[4] = {V.x, V.y, V.z, V.w};
        const float Ns[4] = {N.x, N.y, N.z, N.w};
        const float Rs[4] = {R.x, R.y, R.z, R.w};
        const float Ts[4] = {Tm.x, Tm.y, Tm.z, Tm.w};
#pragma unroll
        for (int i = 0; i < 4; ++i) {
            const float rho = fminf(1.0f, __expf(Ls[i] - Os[i]));
            a[4 * k + i] = Ts[i] * rho;
            d[4 * k + i] = rho * (Rs[i] + Ts[i] * Ns[i] - Vs[i]);
        }
    }
    ((float4*)aL)[2 * t + 0] = make_float4(a[0], a[1], a[2], a[3]);
    ((float4*)aL)[2 * t + 1] = make_float4(a[4], a[5], a[6], a[7]);
    ((float4*)dL)[2 * t + 0] = make_float4(d[0], d[1], d[2], d[3]);
    ((float4*)dL)[2 * t + 1] = make_float4(d[4], d[5], d[6], d[7]);

    float A = 1.0f, D = 0.0f;
#pragma unroll
    for (int i = 0; i < PER_TH; ++i) { D = fmaf(A, d[i], D); A *= a[i]; }

    // wave inclusive suffix scan (lane l: compose of lanes l..63)
    float iA = A, iD = D;
#pragma unroll
    for (int s = 1; s < 64; s <<= 1) {
        const float oA = __shfl_down(iA, s);
        const float oD = __shfl_down(iD, s);
        if (lane + s < 64) { iD = fmaf(iA, oD, iD); iA *= oA; }
    }
    if (lane == 0) { wA[w] = iA; wD[w] = iD; }

    // wave 0: block carry = compose of chunk aggregates (b+1 .. NB-1) applied to 0
    if (w == 0) {
        float cA = 1.0f, cD = 0.0f;
        const int n = NB - 1 - b;
        if (n > 0) {
            const int len = (n + 63) >> 6;               // <=32
            int j0 = b + 1 + lane * len;
            int j1 = j0 + len; if (j1 > NB) j1 = NB;
            for (int j = j0; j < j1; ++j) {              // lane-contiguous, L2-hot
                cD = fmaf(cA, bD[j], cD);
                cA *= bA[j];
            }
#pragma unroll
            for (int s = 1; s < 64; s <<= 1) {
                const float oA = __shfl_down(cA, s);
                const float oD = __shfl_down(cD, s);
                if (lane + s < 64) { cD = fmaf(cA, oD, cD); cA *= oA; }
            }
        }
        if (lane == 0) sVin = cD;
    }
    __syncthreads();                                     // barrier 1

    // ---- phase B: only (iA,iD)+scalars live past here; a,d come back from LDS ----
    float SA = 1.0f, SD = 0.0f;
#pragma unroll
    for (int j = 0; j < NWAVE; ++j) {
        if (j > w) { SD = fmaf(SA, wD[j], SD); SA *= wA[j]; }
    }
    float eA = __shfl_down(iA, 1);
    float eD = __shfl_down(iD, 1);
    if (lane == 63) { eA = 1.0f; eD = 0.0f; }
    const float vin = fmaf(eA * SA, sVin, fmaf(eA, SD, eD));

    // reload a,d from LDS (own slots; compiler cannot forward across the barrier)
    const float4 A0 = ((const float4*)aL)[2 * t + 0];
    const float4 A1 = ((const float4*)aL)[2 * t + 1];
    const float4 D0 = ((const float4*)dL)[2 * t + 0];
    const float4 D1 = ((const float4*)dL)[2 * t + 1];
    const float aa[PER_TH] = {A0.x, A0.y, A0.z, A0.w, A1.x, A1.y, A1.z, A1.w};
    float       dd[PER_TH] = {D0.x, D0.y, D0.z, D0.w, D1.x, D1.y, D1.z, D1.w};

    float v = vin, ss = 0.0f;
#pragma unroll
    for (int i = PER_TH - 1; i >= 0; --i) {
        v = fmaf(aa[i], v, dd[i]);
        dd[i] = v;                                       // ys
        ss = fmaf(v, v, ss);
    }

    // overwrite own aL slots with ys (read-before-write by same thread: safe)
    ((float4*)aL)[2 * t + 0] = make_float4(dd[0], dd[1], dd[2], dd[3]);
    ((float4*)aL)[2 * t + 1] = make_float4(dd[4], dd[5], dd[6], dd[7]);
    __syncthreads();                                     // barrier 2

    // coalesced scalar stores (out+1 is 4B-misaligned for float4)
    const size_t obase = 1 + (size_t)b * CHUNK;
#pragma unroll
    for (int k = 0; k < PER_TH; ++k) out[obase + t + k * BLK] = aL[t + k * BLK];

    // loss: wave butterfly -> LDS -> one double atomic/block; last block finalizes
#pragma unroll
    for (int s = 32; s > 0; s >>= 1) ss += __shfl_xor(ss, s);
    if (lane == 0) rsum[w] = ss;
    __syncthreads();                                     // barrier 3
    if (t == 0) {
        float bs = 0.0f;
#pragma unroll
        for (int j = 0; j < NWAVE; ++j) bs += rsum[j];
        atomicAdd(acc, (double)bs);
        __threadfence();
        const unsigned old = atomicAdd(done, 1u);
        if (old == NB - 1) {
            const double av = __hip_atomic_load(acc, __ATOMIC_ACQUIRE, SCOPE);
            out[0] = (float)(av * (1.0 / (double)T_TOTAL));
        }
    }
}

extern "C" void kernel_launch(void* const* d_in, const int* in_sizes, int n_in,
                              void* d_out, int out_size, void* d_ws, size_t ws_size,
                              hipStream_t stream) {
    const float* lp   = (const float*)d_in[0];
    const float* olp  = (const float*)d_in[1];
    const float* val  = (const float*)d_in[2];
    const float* nval = (const float*)d_in[3];
    const float* rew  = (const float*)d_in[4];
    const float* ter  = (const float*)d_in[5];
    float* out = (float*)d_out;

    double*   acc  = (double*)d_ws;                  // 8B
    unsigned* done = (unsigned*)((char*)d_ws + 8);   // 4B (+4 pad)
    float*    bA   = (float*)((char*)d_ws + 16);     // NB floats
    float*    bD   = bA + NB;                        // ws use ~16.4 KB

    k_agg<<<NB, BLK, 0, stream>>>(lp, olp, val, nval, rew, ter, bA, bD, acc, done);
    k_out<<<NB, BLK, 0, stream>>>(lp, olp, val, nval, rew, ter, bA, bD, out, acc, done);
}

// Round 7
// 198.699 us; speedup vs baseline: 1.1889x; 1.1617x over previous
//
#include <hip/hip_runtime.h>

#define T_TOTAL 4194304
#define CHUNK 4096                // elements per chunk (shared by all passes)
#define NB (T_TOTAL / CHUNK)      // 1024 chunks
#define ABLK 256                  // k_agg block size
#define AWAVE (ABLK / 64)         // 4 waves
#define OBLK 512                  // k_out block size
#define OPER 8                    // elems/thread in k_out
#define OWAVE (OBLK / 64)         // 8 waves
#define SBLK 256                  // k_scan block size
#define SWAVE (SBLK / 64)         // 4 waves
#define SPER (NB / SBLK)          // 4 aggregates per scan thread
#define SCOPE __HIP_MEMORY_SCOPE_AGENT

// Affine transform: T_i maps v_{i+1} -> v_i = a_i*v_{i+1} + d_i.
// Fold over increasing i: D = fmaf(A, d_i, D); A *= a_i.
// Suffix-combine (self=lower idx, other=higher): D = fmaf(A, oD, D); A *= oA.

// ---- pass 1: per-chunk aggregates. 16 elems/thread, all 24 loads issued up front ----
// grid 1024 = 4 blocks/CU; launch_bounds(256,4) caps VGPR at 128 so the load
// cluster (24 float4 dests ~ 96 VGPR) fits at full grid-limited residency.
__global__ __launch_bounds__(ABLK, 4) void k_agg(
    const float* __restrict__ lp, const float* __restrict__ olp,
    const float* __restrict__ val, const float* __restrict__ nval,
    const float* __restrict__ rew, const float* __restrict__ ter,
    float* __restrict__ bA, float* __restrict__ bD,
    double* __restrict__ acc, unsigned* __restrict__ done)
{
    __shared__ float wA[AWAVE], wD[AWAVE];
    const int b = blockIdx.x, t = threadIdx.x;
    const int lane = t & 63, w = t >> 6;
    const size_t base4 = (size_t)b * (CHUNK / 4) + 4 * (size_t)t;

    if (b == 0 && t == 0) { *acc = 0.0; *done = 0u; }   // ws poisoned pre-launch

    // issue all loads first (deep MLP), then compute
    float4 L[4], O[4], V[4], N[4], R[4], Tm[4];
#pragma unroll
    for (int k = 0; k < 4; ++k) {
        L[k]  = ((const float4*)lp)[base4 + k];
        O[k]  = ((const float4*)olp)[base4 + k];
        V[k]  = ((const float4*)val)[base4 + k];
        N[k]  = ((const float4*)nval)[base4 + k];
        R[k]  = ((const float4*)rew)[base4 + k];
        Tm[k] = ((const float4*)ter)[base4 + k];
    }

    float A = 1.0f, D = 0.0f;
#pragma unroll
    for (int k = 0; k < 4; ++k) {
        const float Ls[4] = {L[k].x, L[k].y, L[k].z, L[k].w};
        const float Os[4] = {O[k].x, O[k].y, O[k].z, O[k].w};
        const float Vs[4] = {V[k].x, V[k].y, V[k].z, V[k].w};
        const float Ns[4] = {N[k].x, N[k].y, N[k].z, N[k].w};
        const float Rs[4] = {R[k].x, R[k].y, R[k].z, R[k].w};
        const float Ts[4] = {Tm[k].x, Tm[k].y, Tm[k].z, Tm[k].w};
#pragma unroll
        for (int i = 0; i < 4; ++i) {
            const float rho = fminf(1.0f, __expf(Ls[i] - Os[i]));
            const float ai = Ts[i] * rho;
            const float di = rho * (Rs[i] + Ts[i] * Ns[i] - Vs[i]);
            D = fmaf(A, di, D);
            A *= ai;
        }
    }

    float iA = A, iD = D;
#pragma unroll
    for (int s = 1; s < 64; s <<= 1) {
        const float oA = __shfl_down(iA, s);
        const float oD = __shfl_down(iD, s);
        if (lane + s < 64) { iD = fmaf(iA, oD, iD); iA *= oA; }
    }
    if (lane == 0) { wA[w] = iA; wD[w] = iD; }
    __syncthreads();
    if (t == 0) {
        float BA = 1.0f, BD = 0.0f;
#pragma unroll
        for (int j = 0; j < AWAVE; ++j) { BD = fmaf(BA, wD[j], BD); BA *= wA[j]; }
        bA[b] = BA; bD[b] = BD;
    }
}

// ---- pass 2: scan over 1024 chunk aggregates -> per-chunk carries ----
__global__ __launch_bounds__(SBLK) void k_scan(
    const float* __restrict__ bA, const float* __restrict__ bD,
    float* __restrict__ carry)
{
    __shared__ float wA[SWAVE], wD[SWAVE];
    const int t = threadIdx.x;
    const int lane = t & 63, w = t >> 6;

    float a4[SPER], d4[SPER];
    {
        const float4 A4 = ((const float4*)bA)[t];
        const float4 D4 = ((const float4*)bD)[t];
        a4[0] = A4.x; a4[1] = A4.y; a4[2] = A4.z; a4[3] = A4.w;
        d4[0] = D4.x; d4[1] = D4.y; d4[2] = D4.z; d4[3] = D4.w;
    }
    float A = 1.0f, D = 0.0f;
#pragma unroll
    for (int i = 0; i < SPER; ++i) { D = fmaf(A, d4[i], D); A *= a4[i]; }

    float iA = A, iD = D;
#pragma unroll
    for (int s = 1; s < 64; s <<= 1) {
        const float oA = __shfl_down(iA, s);
        const float oD = __shfl_down(iD, s);
        if (lane + s < 64) { iD = fmaf(iA, oD, iD); iA *= oA; }
    }
    if (lane == 0) { wA[w] = iA; wD[w] = iD; }
    __syncthreads();

    float SA = 1.0f, SD = 0.0f;
#pragma unroll
    for (int j = 0; j < SWAVE; ++j) {
        if (j > w) { SD = fmaf(SA, wD[j], SD); SA *= wA[j]; }
    }

    float eA = __shfl_down(iA, 1);
    float eD = __shfl_down(iD, 1);
    if (lane == 63) { eA = 1.0f; eD = 0.0f; }
    const float ED = fmaf(eA, SD, eD);       // applied to v=0 -> only D matters

    float c4[SPER];
    float v = ED;
    c4[SPER - 1] = v;
#pragma unroll
    for (int i = SPER - 1; i > 0; --i) { v = fmaf(a4[i], v, d4[i]); c4[i - 1] = v; }
    ((float4*)carry)[t] = make_float4(c4[0], c4[1], c4[2], c4[3]);
}

// ---- pass 3: recompute a,d; LDS round-trip across scan barrier; outputs + loss ----
__global__ __launch_bounds__(OBLK) void k_out(
    const float* __restrict__ lp, const float* __restrict__ olp,
    const float* __restrict__ val, const float* __restrict__ nval,
    const float* __restrict__ rew, const float* __restrict__ ter,
    const float* __restrict__ carry,
    float* __restrict__ out, double* __restrict__ acc, unsigned* __restrict__ done)
{
    __shared__ float aL[CHUNK], dL[CHUNK];               // 32 KB
    __shared__ float wA[OWAVE], wD[OWAVE], rsum[OWAVE];
    __shared__ float sVin;

    const int b = blockIdx.x, t = threadIdx.x;
    const int lane = t & 63, w = t >> 6;
    const size_t base4 = (size_t)b * (CHUNK / 4) + 2 * (size_t)t;

    // ---- phase A: load, compute a,d per batch, stash to LDS, fold to (A,D) ----
    float A = 1.0f, D = 0.0f;
#pragma unroll
    for (int k = 0; k < 2; ++k) {
        const float4 L = ((const float4*)lp)[base4 + k];
        const float4 O = ((const float4*)olp)[base4 + k];
        const float4 V = ((const float4*)val)[base4 + k];
        const float4 N = ((const float4*)nval)[base4 + k];
        const float4 R = ((const float4*)rew)[base4 + k];
        const float4 Tm = ((const float4*)ter)[base4 + k];
        const float Ls[4] = {L.x, L.y, L.z, L.w};
        const float Os[4] = {O.x, O.y, O.z, O.w};
        const float Vs[4] = {V.x, V.y, V.z, V.w};
        const float Ns[4] = {N.x, N.y, N.z, N.w};
        const float Rs[4] = {R.x, R.y, R.z, R.w};
        const float Ts[4] = {Tm.x, Tm.y, Tm.z, Tm.w};
        float av[4], dv[4];
#pragma unroll
        for (int i = 0; i < 4; ++i) {
            const float rho = fminf(1.0f, __expf(Ls[i] - Os[i]));
            av[i] = Ts[i] * rho;
            dv[i] = rho * (Rs[i] + Ts[i] * Ns[i] - Vs[i]);
            D = fmaf(A, dv[i], D);
            A *= av[i];
        }
        ((float4*)aL)[2 * t + k] = make_float4(av[0], av[1], av[2], av[3]);
        ((float4*)dL)[2 * t + k] = make_float4(dv[0], dv[1], dv[2], dv[3]);
    }

    // wave inclusive suffix scan
    float iA = A, iD = D;
#pragma unroll
    for (int s = 1; s < 64; s <<= 1) {
        const float oA = __shfl_down(iA, s);
        const float oD = __shfl_down(iD, s);
        if (lane + s < 64) { iD = fmaf(iA, oD, iD); iA *= oA; }
    }
    if (lane == 0) { wA[w] = iA; wD[w] = iD; }
    if (t == 0) sVin = carry[b];                         // one scalar read, no loop
    __syncthreads();                                     // barrier 1

    // ---- phase B: only (iA,iD)+scalars live; a,d return from LDS ----
    float SA = 1.0f, SD = 0.0f;
#pragma unroll
    for (int j = 0; j < OWAVE; ++j) {
        if (j > w) { SD = fmaf(SA, wD[j], SD); SA *= wA[j]; }
    }
    float eA = __shfl_down(iA, 1);
    float eD = __shfl_down(iD, 1);
    if (lane == 63) { eA = 1.0f; eD = 0.0f; }
    const float vin = fmaf(eA * SA, sVin, fmaf(eA, SD, eD));

    const float4 A0 = ((const float4*)aL)[2 * t + 0];
    const float4 A1 = ((const float4*)aL)[2 * t + 1];
    const float4 D0 = ((const float4*)dL)[2 * t + 0];
    const float4 D1 = ((const float4*)dL)[2 * t + 1];
    const float aa[OPER] = {A0.x, A0.y, A0.z, A0.w, A1.x, A1.y, A1.z, A1.w};
    float       dd[OPER] = {D0.x, D0.y, D0.z, D0.w, D1.x, D1.y, D1.z, D1.w};

    float v = vin, ss = 0.0f;
#pragma unroll
    for (int i = OPER - 1; i >= 0; --i) {
        v = fmaf(aa[i], v, dd[i]);
        dd[i] = v;                                       // ys
        ss = fmaf(v, v, ss);
    }

    // overwrite own aL slots with ys (same-thread read-before-write: safe)
    ((float4*)aL)[2 * t + 0] = make_float4(dd[0], dd[1], dd[2], dd[3]);
    ((float4*)aL)[2 * t + 1] = make_float4(dd[4], dd[5], dd[6], dd[7]);
    __syncthreads();                                     // barrier 2

    // coalesced scalar stores (out+1 is 4B-misaligned for float4)
    const size_t obase = 1 + (size_t)b * CHUNK;
#pragma unroll
    for (int k = 0; k < OPER; ++k) out[obase + t + k * OBLK] = aL[t + k * OBLK];

    // loss: wave butterfly -> LDS -> one double atomic/block; last block finalizes
#pragma unroll
    for (int s = 32; s > 0; s >>= 1) ss += __shfl_xor(ss, s);
    if (lane == 0) rsum[w] = ss;
    __syncthreads();                                     // barrier 3
    if (t == 0) {
        float bs = 0.0f;
#pragma unroll
        for (int j = 0; j < OWAVE; ++j) bs += rsum[j];
        atomicAdd(acc, (double)bs);
        __threadfence();
        const unsigned old = atomicAdd(done, 1u);
        if (old == NB - 1) {
            const double av = __hip_atomic_load(acc, __ATOMIC_ACQUIRE, SCOPE);
            out[0] = (float)(av * (1.0 / (double)T_TOTAL));
        }
    }
}

extern "C" void kernel_launch(void* const* d_in, const int* in_sizes, int n_in,
                              void* d_out, int out_size, void* d_ws, size_t ws_size,
                              hipStream_t stream) {
    const float* lp   = (const float*)d_in[0];
    const float* olp  = (const float*)d_in[1];
    const float* val  = (const float*)d_in[2];
    const float* nval = (const float*)d_in[3];
    const float* rew  = (const float*)d_in[4];
    const float* ter  = (const float*)d_in[5];
    float* out = (float*)d_out;

    double*   acc   = (double*)d_ws;                  // 8B
    unsigned* done  = (unsigned*)((char*)d_ws + 8);   // 4B (+4 pad)
    float*    bA    = (float*)((char*)d_ws + 16);     // NB floats
    float*    bD    = bA + NB;
    float*    carry = bD + NB;                        // ws use ~12.3 KB

    k_agg <<<NB, ABLK, 0, stream>>>(lp, olp, val, nval, rew, ter, bA, bD, acc, done);
    k_scan<<<1, SBLK, 0, stream>>>(bA, bD, carry);
    k_out <<<NB, OBLK, 0, stream>>>(lp, olp, val, nval, rew, ter, carry, out, acc, done);
}

// Round 8
// 196.089 us; speedup vs baseline: 1.2047x; 1.0133x over previous
//
#include <hip/hip_runtime.h>

#define T_TOTAL 4194304
#define CHUNK 4096                // elements per chunk
#define NB (T_TOTAL / CHUNK)      // 1024 chunks
#define BLK 256
#define PER 16                    // elems per thread
#define NW (BLK / 64)             // 4 waves
#define SBLK 256                  // k_scan block
#define SW (SBLK / 64)
#define SPER (NB / SBLK)          // 4 aggregates per scan thread
#define SCOPE __HIP_MEMORY_SCOPE_AGENT

// Affine transform: T_i maps v_{i+1} -> v_i = a_i*v_{i+1} + d_i.
// Fold over increasing i: D = fmaf(A, d_i, D); A *= a_i.
// Suffix-combine (self=lower idx, other=higher): D = fmaf(A, oD, D); A *= oA.

// Compute a,d for one float4 group (lane-contiguous global loads).
#define COMPUTE_AD(idx, AV, DV)                                                \
    {                                                                          \
        const float4 L = ((const float4*)lp)[idx];                             \
        const float4 O = ((const float4*)olp)[idx];                            \
        const float4 V = ((const float4*)val)[idx];                            \
        const float4 N = ((const float4*)nval)[idx];                           \
        const float4 R = ((const float4*)rew)[idx];                            \
        const float4 Tm = ((const float4*)ter)[idx];                           \
        const float Ls[4] = {L.x, L.y, L.z, L.w};                              \
        const float Os[4] = {O.x, O.y, O.z, O.w};                              \
        const float Vs[4] = {V.x, V.y, V.z, V.w};                              \
        const float Ns[4] = {N.x, N.y, N.z, N.w};                              \
        const float Rs[4] = {R.x, R.y, R.z, R.w};                              \
        const float Ts[4] = {Tm.x, Tm.y, Tm.z, Tm.w};                          \
        _Pragma("unroll")                                                      \
        for (int _i = 0; _i < 4; ++_i) {                                       \
            const float rho = fminf(1.0f, __expf(Ls[_i] - Os[_i]));            \
            AV[_i] = Ts[_i] * rho;                                             \
            DV[_i] = rho * (Rs[_i] + Ts[_i] * Ns[_i] - Vs[_i]);                \
        }                                                                      \
    }

// ---- pass 1: per-chunk aggregates (lane-contiguous loads + LDS transpose) ----
__global__ __launch_bounds__(BLK) void k_agg(
    const float* __restrict__ lp, const float* __restrict__ olp,
    const float* __restrict__ val, const float* __restrict__ nval,
    const float* __restrict__ rew, const float* __restrict__ ter,
    float* __restrict__ bA, float* __restrict__ bD,
    double* __restrict__ acc, unsigned* __restrict__ done)
{
    __shared__ float aL[CHUNK], dL[CHUNK];               // 32 KB
    __shared__ float wA[NW], wD[NW];
    const int b = blockIdx.x, t = threadIdx.x;
    const int lane = t & 63, w = t >> 6;
    const size_t cb4 = (size_t)b * (CHUNK / 4);

    if (b == 0 && t == 0) { *acc = 0.0; *done = 0u; }   // ws poisoned pre-launch

    // phase A: lane-contiguous loads (f4 idx = cb4 + t + k*BLK), a,d -> LDS
#pragma unroll
    for (int k = 0; k < 4; ++k) {
        const size_t idx = cb4 + t + k * BLK;
        float av[4], dv[4];
        COMPUTE_AD(idx, av, dv);
        ((float4*)aL)[t + k * BLK] = make_float4(av[0], av[1], av[2], av[3]);
        ((float4*)dL)[t + k * BLK] = make_float4(dv[0], dv[1], dv[2], dv[3]);
    }
    __syncthreads();

    // phase B: own contiguous segment (f4s 4t..4t+3; 64B lane stride = 2-way, free)
    float A = 1.0f, D = 0.0f;
#pragma unroll
    for (int k = 0; k < 4; ++k) {
        const float4 a4 = ((const float4*)aL)[4 * t + k];
        const float4 d4 = ((const float4*)dL)[4 * t + k];
        D = fmaf(A, d4.x, D); A *= a4.x;
        D = fmaf(A, d4.y, D); A *= a4.y;
        D = fmaf(A, d4.z, D); A *= a4.z;
        D = fmaf(A, d4.w, D); A *= a4.w;
    }

    float iA = A, iD = D;
#pragma unroll
    for (int s = 1; s < 64; s <<= 1) {
        const float oA = __shfl_down(iA, s);
        const float oD = __shfl_down(iD, s);
        if (lane + s < 64) { iD = fmaf(iA, oD, iD); iA *= oA; }
    }
    if (lane == 0) { wA[w] = iA; wD[w] = iD; }
    __syncthreads();
    if (t == 0) {
        float BA = 1.0f, BD = 0.0f;
#pragma unroll
        for (int j = 0; j < NW; ++j) { BD = fmaf(BA, wD[j], BD); BA *= wA[j]; }
        bA[b] = BA; bD[b] = BD;
    }
}

// ---- pass 2: scan over 1024 chunk aggregates -> per-chunk carries ----
__global__ __launch_bounds__(SBLK) void k_scan(
    const float* __restrict__ bA, const float* __restrict__ bD,
    float* __restrict__ carry)
{
    __shared__ float wA[SW], wD[SW];
    const int t = threadIdx.x;
    const int lane = t & 63, w = t >> 6;

    float a4[SPER], d4[SPER];
    {
        const float4 A4 = ((const float4*)bA)[t];
        const float4 D4 = ((const float4*)bD)[t];
        a4[0] = A4.x; a4[1] = A4.y; a4[2] = A4.z; a4[3] = A4.w;
        d4[0] = D4.x; d4[1] = D4.y; d4[2] = D4.z; d4[3] = D4.w;
    }
    float A = 1.0f, D = 0.0f;
#pragma unroll
    for (int i = 0; i < SPER; ++i) { D = fmaf(A, d4[i], D); A *= a4[i]; }

    float iA = A, iD = D;
#pragma unroll
    for (int s = 1; s < 64; s <<= 1) {
        const float oA = __shfl_down(iA, s);
        const float oD = __shfl_down(iD, s);
        if (lane + s < 64) { iD = fmaf(iA, oD, iD); iA *= oA; }
    }
    if (lane == 0) { wA[w] = iA; wD[w] = iD; }
    __syncthreads();

    float SA = 1.0f, SD = 0.0f;
#pragma unroll
    for (int j = 0; j < SW; ++j) {
        if (j > w) { SD = fmaf(SA, wD[j], SD); SA *= wA[j]; }
    }

    float eA = __shfl_down(iA, 1);
    float eD = __shfl_down(iD, 1);
    if (lane == 63) { eA = 1.0f; eD = 0.0f; }
    const float ED = fmaf(eA, SD, eD);       // applied to v=0 -> only D matters

    float c4[SPER];
    float v = ED;
    c4[SPER - 1] = v;
#pragma unroll
    for (int i = SPER - 1; i > 0; --i) { v = fmaf(a4[i], v, d4[i]); c4[i - 1] = v; }
    ((float4*)carry)[t] = make_float4(c4[0], c4[1], c4[2], c4[3]);
}

// ---- pass 3: lane-contiguous loads + LDS transpose; outputs + fused loss ----
__global__ __launch_bounds__(BLK) void k_out(
    const float* __restrict__ lp, const float* __restrict__ olp,
    const float* __restrict__ val, const float* __restrict__ nval,
    const float* __restrict__ rew, const float* __restrict__ ter,
    const float* __restrict__ carry,
    float* __restrict__ out, double* __restrict__ acc, unsigned* __restrict__ done)
{
    __shared__ float aL[CHUNK], dL[CHUNK];               // 32 KB
    __shared__ float wA[NW], wD[NW], rsum[NW];
    __shared__ float sVin;

    const int b = blockIdx.x, t = threadIdx.x;
    const int lane = t & 63, w = t >> 6;
    const size_t cb4 = (size_t)b * (CHUNK / 4);

    if (t == 0) sVin = carry[b];

    // phase A: lane-contiguous loads, a,d -> LDS (transpose staging)
#pragma unroll
    for (int k = 0; k < 4; ++k) {
        const size_t idx = cb4 + t + k * BLK;
        float av[4], dv[4];
        COMPUTE_AD(idx, av, dv);
        ((float4*)aL)[t + k * BLK] = make_float4(av[0], av[1], av[2], av[3]);
        ((float4*)dL)[t + k * BLK] = make_float4(dv[0], dv[1], dv[2], dv[3]);
    }
    __syncthreads();                                     // barrier 1

    // phase B: own contiguous segment from LDS, fold, wave scan
    float aa[PER], dd[PER];
#pragma unroll
    for (int k = 0; k < 4; ++k) {
        const float4 a4 = ((const float4*)aL)[4 * t + k];
        const float4 d4 = ((const float4*)dL)[4 * t + k];
        aa[4*k+0] = a4.x; aa[4*k+1] = a4.y; aa[4*k+2] = a4.z; aa[4*k+3] = a4.w;
        dd[4*k+0] = d4.x; dd[4*k+1] = d4.y; dd[4*k+2] = d4.z; dd[4*k+3] = d4.w;
    }
    float A = 1.0f, D = 0.0f;
#pragma unroll
    for (int i = 0; i < PER; ++i) { D = fmaf(A, dd[i], D); A *= aa[i]; }

    float iA = A, iD = D;
#pragma unroll
    for (int s = 1; s < 64; s <<= 1) {
        const float oA = __shfl_down(iA, s);
        const float oD = __shfl_down(iD, s);
        if (lane + s < 64) { iD = fmaf(iA, oD, iD); iA *= oA; }
    }
    if (lane == 0) { wA[w] = iA; wD[w] = iD; }
    __syncthreads();                                     // barrier 2

    // suffix over later waves, exclusive within wave, per-thread incoming carry
    float SA = 1.0f, SD = 0.0f;
#pragma unroll
    for (int j = 0; j < NW; ++j) {
        if (j > w) { SD = fmaf(SA, wD[j], SD); SA *= wA[j]; }
    }
    float eA = __shfl_down(iA, 1);
    float eD = __shfl_down(iD, 1);
    if (lane == 63) { eA = 1.0f; eD = 0.0f; }
    const float vin = fmaf(eA * SA, sVin, fmaf(eA, SD, eD));

    // serial backward recurrence; ys overwrite aL own segment (only self reads it)
    float v = vin, ss = 0.0f;
#pragma unroll
    for (int i = PER - 1; i >= 0; --i) {
        v = fmaf(aa[i], v, dd[i]);
        dd[i] = v;
        ss = fmaf(v, v, ss);
    }
#pragma unroll
    for (int k = 0; k < 4; ++k)
        ((float4*)aL)[4 * t + k] =
            make_float4(dd[4*k+0], dd[4*k+1], dd[4*k+2], dd[4*k+3]);
    __syncthreads();                                     // barrier 3

    // lane-contiguous scalar stores (out+1 is 4B-misaligned for float4)
    const size_t obase = 1 + (size_t)b * CHUNK;
#pragma unroll
    for (int k = 0; k < PER; ++k) out[obase + t + k * BLK] = aL[t + k * BLK];

    // loss: wave butterfly -> LDS -> one double atomic/block; last block finalizes
#pragma unroll
    for (int s = 32; s > 0; s >>= 1) ss += __shfl_xor(ss, s);
    if (lane == 0) rsum[w] = ss;
    __syncthreads();                                     // barrier 4
    if (t == 0) {
        float bs = 0.0f;
#pragma unroll
        for (int j = 0; j < NW; ++j) bs += rsum[j];
        atomicAdd(acc, (double)bs);
        __threadfence();
        const unsigned old = atomicAdd(done, 1u);
        if (old == NB - 1) {
            const double av = __hip_atomic_load(acc, __ATOMIC_ACQUIRE, SCOPE);
            out[0] = (float)(av * (1.0 / (double)T_TOTAL));
        }
    }
}

extern "C" void kernel_launch(void* const* d_in, const int* in_sizes, int n_in,
                              void* d_out, int out_size, void* d_ws, size_t ws_size,
                              hipStream_t stream) {
    const float* lp   = (const float*)d_in[0];
    const float* olp  = (const float*)d_in[1];
    const float* val  = (const float*)d_in[2];
    const float* nval = (const float*)d_in[3];
    const float* rew  = (const float*)d_in[4];
    const float* ter  = (const float*)d_in[5];
    float* out = (float*)d_out;

    double*   acc   = (double*)d_ws;                  // 8B
    unsigned* done  = (unsigned*)((char*)d_ws + 8);   // 4B (+4 pad)
    float*    bA    = (float*)((char*)d_ws + 16);     // NB floats
    float*    bD    = bA + NB;
    float*    carry = bD + NB;                        // ws use ~12.3 KB

    k_agg <<<NB, BLK, 0, stream>>>(lp, olp, val, nval, rew, ter, bA, bD, acc, done);
    k_scan<<<1, SBLK, 0, stream>>>(bA, bD, carry);
    k_out <<<NB, BLK, 0, stream>>>(lp, olp, val, nval, rew, ter, carry, out, acc, done);
}